// Round 2
// baseline (360.397 us; speedup 1.0000x reference)
//
#include <hip/hip_runtime.h>

// VectorQuantizer, bit-replicating the harness's numpy fp32 reference.
// x [64,64,64,64] f32 -> flat [N=262144, D=64]; emb [D=64, K=512].
// out = concat(quantized_st flat [16777216], loss [1]) as f32.
//
// numpy semantics replicated exactly:
//   sim[i,k]  = sequential fmaf chain over d=0..63 (OpenBLAS sgemm microkernel:
//               one accumulator per C element, k-ascending vfmadd)
//   z2[i]     = numpy pairwise_sum(n=64): 8 accumulators r[j]=sum sq[8*i+j],
//               combined ((r0+r1)+(r2+r3))+((r4+r5)+(r6+r7))
//   e2[k]     = sequential sum over d ascending (axis-0 reduce)
//   dist      = fl(fl(z2+e2[k]) - 2*sim)   (2*sim exact)
//   argmin    = strict <, first occurrence wins
//   out       = fl(x + fl(q - x))
//
// ws layout (bytes):
//   0      : float  e2[512]
//   4096   : float  et[512*64]   (transposed codebook, row-major per code)
//   135168 : double partials[1024]

#define NROWS 262144
#define D 64
#define K 512

#define WS_E2 0
#define WS_ET 4096
#define WS_PARTIALS 135168

// ---- K1: transpose codebook + numpy-order squared norms ----
__global__ void __launch_bounds__(512) vq_prep(const float* __restrict__ emb, char* ws) {
    float* e2 = (float*)(ws + WS_E2);
    float* et = (float*)(ws + WS_ET);
    int k = threadIdx.x;  // 512 threads, one code each
    float v0 = emb[k];
    et[k * D] = v0;
    float s = __fmul_rn(v0, v0);
    for (int d = 1; d < D; ++d) {
        float v = emb[d * K + k];
        et[k * D + d] = v;
        s = __fadd_rn(s, __fmul_rn(v, v));  // sequential over d, like np axis-0 reduce
    }
    e2[k] = s;
}

// ---- K2: np-exact distance + argmin + gather + loss partials ----
__global__ void __launch_bounds__(256) vq_main(const float* __restrict__ x,
                                               float* __restrict__ out, char* ws) {
    const float* et = (const float*)(ws + WS_ET);
    const float* e2 = (const float*)(ws + WS_E2);
    double* partials = (double*)(ws + WS_PARTIALS);

    const int n = blockIdx.x * 256 + threadIdx.x;

    // z into registers
    float z[64];
    const float4* xr = (const float4*)(x + (size_t)n * D);
#pragma unroll
    for (int q = 0; q < 16; ++q) {
        float4 v = xr[q];
        z[4 * q + 0] = v.x; z[4 * q + 1] = v.y; z[4 * q + 2] = v.z; z[4 * q + 3] = v.w;
    }

    // z2: numpy pairwise_sum over fl(z*z), n=64
    float r[8];
#pragma unroll
    for (int j = 0; j < 8; ++j) r[j] = __fmul_rn(z[j], z[j]);
#pragma unroll
    for (int i = 8; i < 64; i += 8) {
#pragma unroll
        for (int j = 0; j < 8; ++j)
            r[j] = __fadd_rn(r[j], __fmul_rn(z[i + j], z[i + j]));
    }
    float z2 = __fadd_rn(__fadd_rn(__fadd_rn(r[0], r[1]), __fadd_rn(r[2], r[3])),
                         __fadd_rn(__fadd_rn(r[4], r[5]), __fadd_rn(r[6], r[7])));

    // argmin over np-exact dist; codebook reads are wave-uniform -> scalar loads
    float best = 3.4e38f;
    int kb = 0;
    for (int k = 0; k < K; k += 2) {
        const float* ep0 = et + k * D;
        const float* ep1 = ep0 + D;
        float a0 = 0.f, a1 = 0.f;
#pragma unroll
        for (int d = 0; d < D; ++d) {
            a0 = fmaf(z[d], ep0[d], a0);  // sgemm: sequential fma chain, d ascending
            a1 = fmaf(z[d], ep1[d], a1);
        }
        float d0 = __fsub_rn(__fadd_rn(z2, e2[k]),     __fmul_rn(2.0f, a0));
        float d1 = __fsub_rn(__fadd_rn(z2, e2[k + 1]), __fmul_rn(2.0f, a1));
        if (d0 < best) { best = d0; kb = k; }       // strict <: first occurrence wins
        if (d1 < best) { best = d1; kb = k + 1; }
    }

    // gather winning code; out = fl(x + fl(q - x)); loss partial in fp64
    const float* q = et + (size_t)kb * D;
    float4* outr = (float4*)(out + (size_t)n * D);
    double rs = 0.0;
#pragma unroll
    for (int g = 0; g < 16; ++g) {
        float4 o;
        float d0 = __fsub_rn(q[4 * g + 0], z[4 * g + 0]);
        float d1 = __fsub_rn(q[4 * g + 1], z[4 * g + 1]);
        float d2 = __fsub_rn(q[4 * g + 2], z[4 * g + 2]);
        float d3 = __fsub_rn(q[4 * g + 3], z[4 * g + 3]);
        o.x = __fadd_rn(z[4 * g + 0], d0);
        o.y = __fadd_rn(z[4 * g + 1], d1);
        o.z = __fadd_rn(z[4 * g + 2], d2);
        o.w = __fadd_rn(z[4 * g + 3], d3);
        outr[g] = o;
        rs += (double)__fmul_rn(d0, d0) + (double)__fmul_rn(d1, d1) +
              (double)__fmul_rn(d2, d2) + (double)__fmul_rn(d3, d3);
    }

    __shared__ double red[256];
    red[threadIdx.x] = rs;
    __syncthreads();
    for (int s = 128; s > 0; s >>= 1) {
        if (threadIdx.x < s) red[threadIdx.x] += red[threadIdx.x + s];
        __syncthreads();
    }
    if (threadIdx.x == 0) partials[blockIdx.x] = red[0];
}

// ---- K3: finalize loss ----
__global__ void __launch_bounds__(256) vq_finalize(float* __restrict__ out, char* ws) {
    const double* partials = (const double*)(ws + WS_PARTIALS);
    __shared__ double red[256];
    double s = partials[threadIdx.x] + partials[threadIdx.x + 256] +
               partials[threadIdx.x + 512] + partials[threadIdx.x + 768];
    red[threadIdx.x] = s;
    __syncthreads();
    for (int st = 128; st > 0; st >>= 1) {
        if (threadIdx.x < st) red[threadIdx.x] += red[threadIdx.x + st];
        __syncthreads();
    }
    if (threadIdx.x == 0) {
        out[16777216] = (float)(1.25 * red[0] / 16777216.0);
    }
}

extern "C" void kernel_launch(void* const* d_in, const int* in_sizes, int n_in,
                              void* d_out, int out_size, void* d_ws, size_t ws_size,
                              hipStream_t stream) {
    const float* x   = (const float*)d_in[0];
    const float* emb = (const float*)d_in[1];
    float* out = (float*)d_out;
    char* ws = (char*)d_ws;

    vq_prep<<<1, 512, 0, stream>>>(emb, ws);
    vq_main<<<NROWS / 256, 256, 0, stream>>>(x, out, ws);
    vq_finalize<<<1, 256, 0, stream>>>(out, ws);
}